// Round 1
// baseline (29380.118 us; speedup 1.0000x reference)
//
#include <hip/hip_runtime.h>
#include <math.h>

#define SEQT 2048
#define BATCH 256
#define INDIM 64
#define HDIM 128

// exact GELU (approximate=False): 0.5*x*(1+erf(x/sqrt(2)))
__device__ __forceinline__ float gelu_exact(float x) {
    return 0.5f * x * (1.0f + erff(x * 0.70710678118654752f));
}

// One workgroup per batch row. 384 threads = 6 waves, wave-specialized:
//   tid [0,128)   g0: h0[t]   = gelu(Wh0 @ h0[t-1] + Win0 @ x[t])
//   tid [128,256) g1: p1[t-1] = Win1 @ h0[t-1]; lanes<64 also prefetch x
//   tid [256,384) g2: h1[t-2] = gelu(Wh1 @ h1[t-3] + p1[t-2]); stream y1 out
// Software pipeline lag keeps all groups independent within an iteration;
// single __syncthreads per step; ping-pong LDS buffers by parity.
__global__ __launch_bounds__(384, 1) void rnn_scan_kernel(
    const float* __restrict__ seq,
    const float* __restrict__ Win0, const float* __restrict__ Wh0,
    const float* __restrict__ Win1, const float* __restrict__ Wh1,
    const float* __restrict__ h00, const float* __restrict__ h01,
    float* __restrict__ out)
{
    const int b = blockIdx.x;
    const int tid = threadIdx.x;

    __shared__ __align__(16) float xbuf[2][INDIM];
    __shared__ __align__(16) float h0buf[2][HDIM];
    __shared__ __align__(16) float h1buf[2][HDIM];
    __shared__ __align__(16) float p1buf[2][HDIM];

    // Weight rows in registers. Shared array so the register allocator
    // assigns ONE 192-reg block for all three roles (roles are exclusive).
    float w[192];

    if (tid < 128) {
        const int j = tid;
        #pragma unroll
        for (int k = 0; k < INDIM; k += 4) {
            float4 v = *reinterpret_cast<const float4*>(&Win0[j * INDIM + k]);
            w[k] = v.x; w[k + 1] = v.y; w[k + 2] = v.z; w[k + 3] = v.w;
        }
        #pragma unroll
        for (int k = 0; k < HDIM; k += 4) {
            float4 v = *reinterpret_cast<const float4*>(&Wh0[j * HDIM + k]);
            w[64 + k] = v.x; w[64 + k + 1] = v.y; w[64 + k + 2] = v.z; w[64 + k + 3] = v.w;
        }
    } else if (tid < 256) {
        const int j = tid - 128;
        #pragma unroll
        for (int k = 0; k < HDIM; k += 4) {
            float4 v = *reinterpret_cast<const float4*>(&Win1[j * HDIM + k]);
            w[k] = v.x; w[k + 1] = v.y; w[k + 2] = v.z; w[k + 3] = v.w;
        }
    } else {
        const int j = tid - 256;
        #pragma unroll
        for (int k = 0; k < HDIM; k += 4) {
            float4 v = *reinterpret_cast<const float4*>(&Wh1[j * HDIM + k]);
            w[k] = v.x; w[k + 1] = v.y; w[k + 2] = v.z; w[k + 3] = v.w;
        }
    }

    // x prefetch registers (used by g1 lanes with j<64 only)
    float xA = 0.0f, xB = 0.0f;
    if (tid >= 128 && tid < 192) {
        const int j = tid - 128;
        xbuf[0][j] = seq[(size_t)0 * BATCH * INDIM + (size_t)b * INDIM + j];
        xA = seq[(size_t)1 * BATCH * INDIM + (size_t)b * INDIM + j];
        xB = seq[(size_t)2 * BATCH * INDIM + (size_t)b * INDIM + j];
    }
    if (tid < 128) {
        h0buf[1][tid] = h00[tid];   // h0[-1] lives at parity 1 (read at t=0)
        h1buf[1][tid] = h01[tid];   // h1[-1] lives at parity 1 (read at iter 2)
    }
    __syncthreads();

    for (int t = 0; t < SEQT + 2; ++t) {
        const int par = t & 1;

        if (tid < 128) {
            // ---- g0: h0[t] for t in [0, SEQT) ----
            if (t < SEQT) {
                const float* hp = h0buf[par ^ 1];   // h0[t-1]
                const float* xp = xbuf[par];        // x[t]
                float a0 = 0.f, a1 = 0.f, a2 = 0.f, a3 = 0.f;
                #pragma unroll
                for (int k = 0; k < INDIM; k += 4) {
                    float4 hv = *reinterpret_cast<const float4*>(&xp[k]);
                    a0 += w[k]     * hv.x;
                    a1 += w[k + 1] * hv.y;
                    a2 += w[k + 2] * hv.z;
                    a3 += w[k + 3] * hv.w;
                }
                #pragma unroll
                for (int k = 0; k < HDIM; k += 4) {
                    float4 hv = *reinterpret_cast<const float4*>(&hp[k]);
                    a0 += w[64 + k]     * hv.x;
                    a1 += w[64 + k + 1] * hv.y;
                    a2 += w[64 + k + 2] * hv.z;
                    a3 += w[64 + k + 3] * hv.w;
                }
                float s = (a0 + a1) + (a2 + a3);
                h0buf[par][tid] = gelu_exact(s);
            }
        } else if (tid < 256) {
            const int j = tid - 128;
            // ---- g1: xin1[t-1] = Win1 @ h0[t-1], for t in [1, SEQT] ----
            if (t >= 1 && t <= SEQT) {
                const float* hp = h0buf[par ^ 1];   // h0[t-1]
                float a0 = 0.f, a1 = 0.f, a2 = 0.f, a3 = 0.f;
                #pragma unroll
                for (int k = 0; k < HDIM; k += 4) {
                    float4 hv = *reinterpret_cast<const float4*>(&hp[k]);
                    a0 += w[k]     * hv.x;
                    a1 += w[k + 1] * hv.y;
                    a2 += w[k + 2] * hv.z;
                    a3 += w[k + 3] * hv.w;
                }
                p1buf[par ^ 1][j] = (a0 + a1) + (a2 + a3);  // slot (t-1)&1
            }
            // ---- x prefetch: stage x[t+1] into xbuf[(t+1)&1]; issue x[t+3] ----
            if (j < 64 && t <= SEQT - 2) {
                xbuf[par ^ 1][j] = xA;   // compiler inserts vmcnt wait (issued 2 iters ago)
                xA = xB;
                int tn = t + 3; if (tn > SEQT - 1) tn = SEQT - 1;
                xB = seq[(size_t)tn * BATCH * INDIM + (size_t)b * INDIM + j];
            }
        } else {
            const int j = tid - 256;
            // ---- g2: h1[tt] with tt = t-2, for t in [2, SEQT+1] ----
            if (t >= 2) {
                const int tt = t - 2;
                const float* hp = h1buf[par ^ 1];   // h1[tt-1]
                float a0 = 0.f, a1 = 0.f, a2 = 0.f, a3 = 0.f;
                #pragma unroll
                for (int k = 0; k < HDIM; k += 4) {
                    float4 hv = *reinterpret_cast<const float4*>(&hp[k]);
                    a0 += w[k]     * hv.x;
                    a1 += w[k + 1] * hv.y;
                    a2 += w[k + 2] * hv.z;
                    a3 += w[k + 3] * hv.w;
                }
                float s = (a0 + a1) + (a2 + a3) + p1buf[par][j];  // + xin1[tt]
                float g = gelu_exact(s);
                h1buf[par][j] = g;   // slot tt&1 == par
                out[((size_t)tt * BATCH + b) * HDIM + j] = g;
            }
        }
        __syncthreads();
    }

    // final hiddens: h0[2047] in h0buf[1], h1[2047] in h1buf[1]
    const size_t YSZ = (size_t)SEQT * BATCH * HDIM;
    if (tid < 128) {
        out[YSZ + (size_t)b * HDIM + tid] = h0buf[1][tid];
    } else if (tid < 256) {
        out[YSZ + (size_t)BATCH * HDIM + (size_t)b * HDIM + (tid - 128)] = h1buf[1][tid - 128];
    }
}

extern "C" void kernel_launch(void* const* d_in, const int* in_sizes, int n_in,
                              void* d_out, int out_size, void* d_ws, size_t ws_size,
                              hipStream_t stream) {
    const float* seq  = (const float*)d_in[0];
    const float* Win0 = (const float*)d_in[1];
    const float* Wh0  = (const float*)d_in[2];
    const float* Win1 = (const float*)d_in[3];
    const float* Wh1  = (const float*)d_in[4];
    const float* h00  = (const float*)d_in[5];
    const float* h01  = (const float*)d_in[6];

    rnn_scan_kernel<<<dim3(BATCH), dim3(384), 0, stream>>>(
        seq, Win0, Wh0, Win1, Wh1, h00, h01, (float*)d_out);
}

// Round 2
// 7217.353 us; speedup vs baseline: 4.0708x; 4.0708x over previous
//
#include <hip/hip_runtime.h>
#include <math.h>

#define SEQT 2048
#define BATCH 256
#define INDIM 64
#define HDIM 128

// exact GELU (approximate=False): 0.5*x*(1+erf(x/sqrt(2)))
__device__ __forceinline__ float gelu_exact(float x) {
    return 0.5f * x * (1.0f + erff(x * 0.70710678118654752f));
}

// One workgroup per batch row. 512 threads = 8 waves = 2/SIMD, 4 groups of 128:
//   g0: h0[t]     = gelu(Wh0 @ h0[t-1] + xin0[t])          (w = Wh0 row, 128)
//   g1: xin1[t-1] = Win1 @ h0[t-1]                         (w = Win1 row, 128)
//   g2: h1[t-2]   = gelu(Wh1 @ h1[t-3] + xin1[t-2]); store (w = Wh1 row, 128)
//   g3: xin0[t+1] = Win0 @ x[t+1]; prefetch x              (w = Win0 row, 64)
// Single float w[128] union across exclusive groups -> one register block.
// One __syncthreads per step; all LDS state ping-pongs by parity.
__global__ __launch_bounds__(512)
__attribute__((amdgpu_waves_per_eu(1, 2)))
void rnn_scan_kernel(
    const float* __restrict__ seq,
    const float* __restrict__ Win0, const float* __restrict__ Wh0,
    const float* __restrict__ Win1, const float* __restrict__ Wh1,
    const float* __restrict__ h00, const float* __restrict__ h01,
    float* __restrict__ out)
{
    const int b = blockIdx.x;
    const int tid = threadIdx.x;
    const int g = tid >> 7;     // group 0..3
    const int j = tid & 127;    // index within group

    __shared__ __align__(16) float xbuf[2][INDIM];
    __shared__ __align__(16) float h0buf[2][HDIM];
    __shared__ __align__(16) float h1buf[2][HDIM];
    __shared__ __align__(16) float p1buf[2][HDIM];   // xin1 pipeline
    __shared__ __align__(16) float x0buf[2][HDIM];   // xin0 pipeline

    // Weight row in registers; groups are exclusive so one 128-reg block serves all.
    float w[HDIM];

    if (g == 0) {
        #pragma unroll
        for (int k = 0; k < HDIM; k += 4) {
            float4 v = *reinterpret_cast<const float4*>(&Wh0[j * HDIM + k]);
            w[k] = v.x; w[k + 1] = v.y; w[k + 2] = v.z; w[k + 3] = v.w;
        }
    } else if (g == 1) {
        #pragma unroll
        for (int k = 0; k < HDIM; k += 4) {
            float4 v = *reinterpret_cast<const float4*>(&Win1[j * HDIM + k]);
            w[k] = v.x; w[k + 1] = v.y; w[k + 2] = v.z; w[k + 3] = v.w;
        }
    } else if (g == 2) {
        #pragma unroll
        for (int k = 0; k < HDIM; k += 4) {
            float4 v = *reinterpret_cast<const float4*>(&Wh1[j * HDIM + k]);
            w[k] = v.x; w[k + 1] = v.y; w[k + 2] = v.z; w[k + 3] = v.w;
        }
    } else {
        #pragma unroll
        for (int k = 0; k < INDIM; k += 4) {
            float4 v = *reinterpret_cast<const float4*>(&Win0[j * INDIM + k]);
            w[k] = v.x; w[k + 1] = v.y; w[k + 2] = v.z; w[k + 3] = v.w;
        }
    }

    // x prefetch registers (g3 lanes j<64 only)
    float xA = 0.0f, xB = 0.0f;
    if (g == 3 && j < 64) {
        const size_t base = (size_t)b * INDIM + j;
        xbuf[0][j] = seq[(size_t)0 * BATCH * INDIM + base];
        xbuf[1][j] = seq[(size_t)1 * BATCH * INDIM + base];
        xA = seq[(size_t)2 * BATCH * INDIM + base];
        xB = seq[(size_t)3 * BATCH * INDIM + base];
    }
    if (g == 0) h0buf[1][j] = h00[j];   // h0[-1] at parity 1
    if (g == 1) h1buf[1][j] = h01[j];   // h1[-1] at parity 1
    __syncthreads();

    // prologue: xin0[0]
    if (g == 3) {
        float a0 = 0.f, a1 = 0.f, a2 = 0.f, a3 = 0.f;
        #pragma unroll
        for (int k = 0; k < INDIM; k += 4) {
            float4 hv = *reinterpret_cast<const float4*>(&xbuf[0][k]);
            a0 += w[k]     * hv.x;
            a1 += w[k + 1] * hv.y;
            a2 += w[k + 2] * hv.z;
            a3 += w[k + 3] * hv.w;
        }
        x0buf[0][j] = (a0 + a1) + (a2 + a3);
    }
    __syncthreads();

    for (int t = 0; t < SEQT + 2; ++t) {
        const int par = t & 1;

        if (g == 0) {
            // ---- h0[t] = gelu(Wh0 @ h0[t-1] + xin0[t]), t in [0, SEQT) ----
            if (t < SEQT) {
                const float* hp = h0buf[par ^ 1];
                float a0 = 0.f, a1 = 0.f, a2 = 0.f, a3 = 0.f;
                #pragma unroll
                for (int k = 0; k < HDIM; k += 4) {
                    float4 hv = *reinterpret_cast<const float4*>(&hp[k]);
                    a0 += w[k]     * hv.x;
                    a1 += w[k + 1] * hv.y;
                    a2 += w[k + 2] * hv.z;
                    a3 += w[k + 3] * hv.w;
                }
                float s = (a0 + a1) + (a2 + a3) + x0buf[par][j];
                h0buf[par][j] = gelu_exact(s);
            }
        } else if (g == 1) {
            // ---- xin1[t-1] = Win1 @ h0[t-1], t in [1, SEQT] ----
            if (t >= 1 && t <= SEQT) {
                const float* hp = h0buf[par ^ 1];
                float a0 = 0.f, a1 = 0.f, a2 = 0.f, a3 = 0.f;
                #pragma unroll
                for (int k = 0; k < HDIM; k += 4) {
                    float4 hv = *reinterpret_cast<const float4*>(&hp[k]);
                    a0 += w[k]     * hv.x;
                    a1 += w[k + 1] * hv.y;
                    a2 += w[k + 2] * hv.z;
                    a3 += w[k + 3] * hv.w;
                }
                p1buf[par ^ 1][j] = (a0 + a1) + (a2 + a3);   // slot (t-1)&1
            }
        } else if (g == 2) {
            // ---- h1[tt], tt = t-2: gelu(Wh1 @ h1[tt-1] + xin1[tt]); store ----
            if (t >= 2) {
                const int tt = t - 2;
                const float* hp = h1buf[par ^ 1];
                float a0 = 0.f, a1 = 0.f, a2 = 0.f, a3 = 0.f;
                #pragma unroll
                for (int k = 0; k < HDIM; k += 4) {
                    float4 hv = *reinterpret_cast<const float4*>(&hp[k]);
                    a0 += w[k]     * hv.x;
                    a1 += w[k + 1] * hv.y;
                    a2 += w[k + 2] * hv.z;
                    a3 += w[k + 3] * hv.w;
                }
                float s = (a0 + a1) + (a2 + a3) + p1buf[par][j];
                float gv = gelu_exact(s);
                h1buf[par][j] = gv;   // parity tt&1 == par
                out[((size_t)tt * BATCH + b) * HDIM + j] = gv;
            }
        } else {
            // ---- xin0[t+1] = Win0 @ x[t+1], t in [0, SEQT-2] ----
            if (t <= SEQT - 2) {
                const float* xp = xbuf[par ^ 1];   // x[t+1]
                float a0 = 0.f, a1 = 0.f, a2 = 0.f, a3 = 0.f;
                #pragma unroll
                for (int k = 0; k < INDIM; k += 4) {
                    float4 hv = *reinterpret_cast<const float4*>(&xp[k]);
                    a0 += w[k]     * hv.x;
                    a1 += w[k + 1] * hv.y;
                    a2 += w[k + 2] * hv.z;
                    a3 += w[k + 3] * hv.w;
                }
                x0buf[par ^ 1][j] = (a0 + a1) + (a2 + a3);   // slot (t+1)&1
            }
            // ---- stage x[t+2] into xbuf[(t+2)&1]; issue load of x[t+4] ----
            if (j < 64 && t <= SEQT - 3) {
                xbuf[par][j] = xA;       // x[t+2], loaded 2 iters ago
                xA = xB;
                int tn = t + 4; if (tn > SEQT - 1) tn = SEQT - 1;
                xB = seq[(size_t)tn * BATCH * INDIM + (size_t)b * INDIM + j];
            }
        }
        __syncthreads();
    }

    // final hiddens: h0[2047] and h1[2047] both live at parity 1
    const size_t YSZ = (size_t)SEQT * BATCH * HDIM;
    if (g == 0) {
        out[YSZ + (size_t)b * HDIM + j] = h0buf[1][j];
    } else if (g == 1) {
        out[YSZ + (size_t)BATCH * HDIM + (size_t)b * HDIM + j] = h1buf[1][j];
    }
}

extern "C" void kernel_launch(void* const* d_in, const int* in_sizes, int n_in,
                              void* d_out, int out_size, void* d_ws, size_t ws_size,
                              hipStream_t stream) {
    const float* seq  = (const float*)d_in[0];
    const float* Win0 = (const float*)d_in[1];
    const float* Wh0  = (const float*)d_in[2];
    const float* Win1 = (const float*)d_in[3];
    const float* Wh1  = (const float*)d_in[4];
    const float* h00  = (const float*)d_in[5];
    const float* h01  = (const float*)d_in[6];

    rnn_scan_kernel<<<dim3(BATCH), dim3(512), 0, stream>>>(
        seq, Win0, Wh0, Win1, Wh1, h00, h01, (float*)d_out);
}

// Round 3
// 2831.859 us; speedup vs baseline: 10.3749x; 2.5486x over previous
//
#include <hip/hip_runtime.h>
#include <math.h>

#define SEQT 2048
#define BATCH 256
#define INDIM 64
#define HDIM 128

// exact GELU (approximate=False): 0.5*x*(1+erf(x/sqrt(2)))
__device__ __forceinline__ float gelu_exact(float x) {
    return 0.5f * x * (1.0f + erff(x * 0.70710678118654752f));
}

// broadcast h[k] from lane k of vh via v_readlane (SGPR path, no LDS traffic)
__device__ __forceinline__ float rdlane(float v, int k) {
    return __int_as_float(__builtin_amdgcn_readlane(__float_as_int(v), k));
}

// 64-MAC dot: per-lane weights w[0..63] against broadcast h[k]=vh[lane k]
__device__ __forceinline__ float dot64(const float* w, float vh) {
    float a0 = 0.f, a1 = 0.f, a2 = 0.f, a3 = 0.f;
    #pragma unroll
    for (int k = 0; k < 64; k += 4) {
        a0 = fmaf(w[k],     rdlane(vh, k),     a0);
        a1 = fmaf(w[k + 1], rdlane(vh, k + 1), a1);
        a2 = fmaf(w[k + 2], rdlane(vh, k + 2), a2);
        a3 = fmaf(w[k + 3], rdlane(vh, k + 3), a3);
    }
    return (a0 + a1) + (a2 + a3);
}

// One workgroup per batch row. 896 threads = 14 waves.
// Each wave owns a 64-output x 64-K slice of one matvec (w[64] per lane, ~90 VGPR):
//   waves 0-3 : Wh0 @ h0[t-1]      (oh = w&1, kh = w>>1)   -> h0[t] (with xin0)
//   waves 4-7 : Win1 @ h0[t-1]                              -> xin1[t-1]
//   waves 8-11: Wh1 @ h1[t-3]                               -> h1[t-2] (with xin1)
//   waves 12-13: Win0 @ x[t+1] (K=64, no split; oh = w-12)  -> xin0[t+1]
// h broadcast: 1 ds_read_b32/lane/step + v_readlane per MAC (no LDS BW amplification).
// K-half partials combine via red[][] with a mid-step barrier (2 barriers/step).
__global__ __launch_bounds__(896, 1)
void rnn_scan_kernel(
    const float* __restrict__ seq,
    const float* __restrict__ Win0, const float* __restrict__ Wh0,
    const float* __restrict__ Win1, const float* __restrict__ Wh1,
    const float* __restrict__ h00, const float* __restrict__ h01,
    float* __restrict__ out)
{
    const int b = blockIdx.x;
    const int tid = threadIdx.x;
    const int wv = tid >> 6;     // wave 0..13
    const int lane = tid & 63;

    int grp, oh, kh;
    if (wv < 12) { grp = wv >> 2; const int m = wv & 3; oh = m & 1; kh = m >> 1; }
    else         { grp = 3; oh = wv - 12; kh = 0; }
    const int o = oh * 64 + lane;          // output index 0..127

    __shared__ float xbuf[2][INDIM];
    __shared__ float h0buf[2][HDIM];
    __shared__ float h1buf[2][HDIM];
    __shared__ float p1buf[2][HDIM];   // xin1 pipeline
    __shared__ float x0buf[2][HDIM];   // xin0 pipeline
    __shared__ float red[3][HDIM];     // K-half partial sums

    // per-lane weight slice: 64 floats (registers)
    float w[64];
    {
        const float* Wsel = (grp == 0) ? Wh0 : (grp == 1) ? Win1 : (grp == 2) ? Wh1 : Win0;
        const int stride = (grp == 3) ? INDIM : HDIM;
        const int coff = (grp == 3) ? 0 : kh * 64;
        #pragma unroll
        for (int j = 0; j < 64; j += 4) {
            float4 v = *reinterpret_cast<const float4*>(&Wsel[o * stride + coff + j]);
            w[j] = v.x; w[j + 1] = v.y; w[j + 2] = v.z; w[j + 3] = v.w;
        }
    }

    // x prefetch registers (wave 12 only; j = lane)
    float xA = 0.f, xB = 0.f;
    if (wv == 12) {
        const size_t base = (size_t)b * INDIM + lane;
        xbuf[0][lane] = seq[base];
        xbuf[1][lane] = seq[(size_t)BATCH * INDIM + base];
        xA = seq[(size_t)2 * BATCH * INDIM + base];
        xB = seq[(size_t)3 * BATCH * INDIM + base];
    }
    if (wv == 0) h0buf[1][lane] = h00[lane];
    if (wv == 1) h0buf[1][64 + lane] = h00[64 + lane];
    if (wv == 2) h1buf[1][lane] = h01[lane];
    if (wv == 3) h1buf[1][64 + lane] = h01[64 + lane];
    __syncthreads();

    // prologue: xin0[0] = Win0 @ x[0]
    if (grp == 3) {
        x0buf[0][o] = dot64(w, xbuf[0][lane]);
    }
    __syncthreads();

    for (int t = 0; t < SEQT + 2; ++t) {
        const int par = t & 1;
        float acc = 0.f;

        // ---- phase A: 64x64 partial matvecs ----
        if (grp == 0) {
            if (t < SEQT) {
                acc = dot64(w, h0buf[par ^ 1][kh * 64 + lane]);   // h0[t-1]
                if (kh == 1) red[0][o] = acc;
            }
        } else if (grp == 1) {
            if (t >= 1 && t <= SEQT) {
                acc = dot64(w, h0buf[par ^ 1][kh * 64 + lane]);   // h0[t-1]
                if (kh == 1) red[1][o] = acc;
            }
        } else if (grp == 2) {
            if (t >= 2) {
                acc = dot64(w, h1buf[par ^ 1][kh * 64 + lane]);   // h1[t-3]
                if (kh == 1) red[2][o] = acc;
            }
        } else {
            if (t <= SEQT - 2) {
                acc = dot64(w, xbuf[par ^ 1][lane]);              // x[t+1]
            }
        }
        __syncthreads();

        // ---- phase B: combine halves, nonlinearity, state/stream writes ----
        if (grp == 0) {
            if (t < SEQT && kh == 0) {
                float s = acc + red[0][o] + x0buf[par][o];
                h0buf[par][o] = gelu_exact(s);
            }
        } else if (grp == 1) {
            if (t >= 1 && t <= SEQT && kh == 0) {
                p1buf[par ^ 1][o] = acc + red[1][o];              // xin1[t-1]
            }
        } else if (grp == 2) {
            if (t >= 2 && kh == 0) {
                const int tt = t - 2;
                float s = acc + red[2][o] + p1buf[par][o];
                float gv = gelu_exact(s);
                h1buf[par][o] = gv;
                out[((size_t)tt * BATCH + b) * HDIM + o] = gv;
            }
        } else {
            if (t <= SEQT - 2) x0buf[par ^ 1][o] = acc;           // xin0[t+1]
            if (wv == 12 && t <= SEQT - 3) {
                xbuf[par][lane] = xA;   // x[t+2] (issued 2 steps ago)
                xA = xB;
                int tn = t + 4; if (tn > SEQT - 1) tn = SEQT - 1;
                xB = seq[(size_t)tn * BATCH * INDIM + (size_t)b * INDIM + lane];
            }
        }
        __syncthreads();
    }

    // final hiddens: h0[2047] and h1[2047] both live at parity 1
    const size_t YSZ = (size_t)SEQT * BATCH * HDIM;
    if (wv == 0) out[YSZ + (size_t)b * HDIM + lane] = h0buf[1][lane];
    if (wv == 1) out[YSZ + (size_t)b * HDIM + 64 + lane] = h0buf[1][64 + lane];
    if (wv == 2) out[YSZ + (size_t)BATCH * HDIM + (size_t)b * HDIM + lane] = h1buf[1][lane];
    if (wv == 3) out[YSZ + (size_t)BATCH * HDIM + (size_t)b * HDIM + 64 + lane] = h1buf[1][64 + lane];
}

extern "C" void kernel_launch(void* const* d_in, const int* in_sizes, int n_in,
                              void* d_out, int out_size, void* d_ws, size_t ws_size,
                              hipStream_t stream) {
    const float* seq  = (const float*)d_in[0];
    const float* Win0 = (const float*)d_in[1];
    const float* Wh0  = (const float*)d_in[2];
    const float* Win1 = (const float*)d_in[3];
    const float* Wh1  = (const float*)d_in[4];
    const float* h00  = (const float*)d_in[5];
    const float* h01  = (const float*)d_in[6];

    rnn_scan_kernel<<<dim3(BATCH), dim3(896), 0, stream>>>(
        seq, Win0, Wh0, Win1, Wh1, h00, h01, (float*)d_out);
}

// Round 4
// 1632.934 us; speedup vs baseline: 17.9922x; 1.7342x over previous
//
#include <hip/hip_runtime.h>
#include <math.h>

#define SEQT 2048
#define BATCH 256
#define INDIM 64
#define HDIM 128

typedef float v2f __attribute__((ext_vector_type(2)));

// exact GELU (approximate=False): 0.5*x*(1+erf(x/sqrt(2)))
__device__ __forceinline__ float gelu_exact(float x) {
    return 0.5f * x * (1.0f + erff(x * 0.70710678118654752f));
}

__device__ __forceinline__ float rdl(float v, int k) {
    return __int_as_float(__builtin_amdgcn_readlane(__float_as_int(v), k));
}

// dot over K-slice [KOFF, KOFF+64). h layout: lane m holds h[2m] (hx) and h[2m+1] (hy).
// Each lane accumulates 2 outputs (float2). 64 readlane + 64 pk_fma.
template <int KOFF>
__device__ __forceinline__ v2f dot64_pair(const v2f* w2, float hx, float hy) {
    v2f a0 = {0.f, 0.f}, a1 = {0.f, 0.f};
    #pragma unroll
    for (int j = 0; j < 64; j += 2) {
        const int m = (KOFF + j) >> 1;          // compile-time lane index
        float ha = rdl(hx, m);                  // h[KOFF+j]
        float hb = rdl(hy, m);                  // h[KOFF+j+1]
        a0 += w2[j]     * (v2f){ha, ha};
        a1 += w2[j + 1] * (v2f){hb, hb};
    }
    return a0 + a1;
}

// dot over 64 K where lane j holds value h[j] in vh (single float).
__device__ __forceinline__ v2f dot64_single(const v2f* w2, float vh) {
    v2f a0 = {0.f, 0.f}, a1 = {0.f, 0.f};
    #pragma unroll
    for (int j = 0; j < 64; j += 2) {
        float ha = rdl(vh, j);
        float hb = rdl(vh, j + 1);
        a0 += w2[j]     * (v2f){ha, ha};
        a1 += w2[j + 1] * (v2f){hb, hb};
    }
    return a0 + a1;
}

// One workgroup per batch row. 448 threads = 7 waves, ONE barrier per step.
// Lane l of each wave owns outputs o=2l, 2l+1 (float2). Weights: w2[64] float2.
//   wv0/1: rec0 kh={0,1}: combine h0[t-1] (gelu, in-reg) then Wh0-slice @ h0[t-1]
//   wv2/3: rec1 kh={0,1}: combine h1[t-3] (gelu, in-reg, store y1) then Wh1 @ h1[t-3]
//   wv4/5: xin1 kh={0,1}: Win1-slice @ h0[t-2] (h0 via small LDS copy)
//   wv6  : xin0: Win0 @ x[t+1] (x broadcast from own regs, prefetch depth 3)
// Partials flow through parity-indexed LDS; xin0 uses a depth-4 ring.
__global__ __launch_bounds__(448, 2)
void rnn_scan_kernel(
    const float* __restrict__ seq,
    const float* __restrict__ Win0, const float* __restrict__ Wh0,
    const float* __restrict__ Win1, const float* __restrict__ Wh1,
    const float* __restrict__ h00, const float* __restrict__ h01,
    float* __restrict__ out)
{
    const int b = blockIdx.x;
    const int tid = threadIdx.x;
    const int wv = tid >> 6;
    const int l = tid & 63;

    __shared__ __align__(16) v2f red0[2][2][64];   // rec0 partials [target-parity][kh][lane]
    __shared__ __align__(16) v2f red1[2][2][64];   // xin1 partials [value-parity][kh][lane]
    __shared__ __align__(16) v2f red2[2][2][64];   // rec1 partials [target-parity][kh][lane]
    __shared__ __align__(16) v2f h0buf[2][64];     // h0 history for xin1 waves
    __shared__ __align__(16) v2f x0ring[4][64];    // xin0 ring (depth 4: 2-deep races)

    // ---- load per-lane weight slice: rows 2l, 2l+1, interleaved as float2 ----
    v2f w2[64];
    {
        const float* W;
        int stride, c0;
        if (wv < 2)      { W = Wh0;  stride = HDIM;  c0 = (wv & 1) * 64; }
        else if (wv < 4) { W = Wh1;  stride = HDIM;  c0 = (wv & 1) * 64; }
        else if (wv < 6) { W = Win1; stride = HDIM;  c0 = (wv & 1) * 64; }
        else             { W = Win0; stride = INDIM; c0 = 0; }
        const float* ra = &W[(2 * l) * stride + c0];
        const float* rb = &W[(2 * l + 1) * stride + c0];
        #pragma unroll
        for (int j = 0; j < 64; j += 4) {
            float4 a = *reinterpret_cast<const float4*>(&ra[j]);
            float4 bq = *reinterpret_cast<const float4*>(&rb[j]);
            w2[j]     = (v2f){a.x, bq.x};
            w2[j + 1] = (v2f){a.y, bq.y};
            w2[j + 2] = (v2f){a.z, bq.z};
            w2[j + 3] = (v2f){a.w, bq.w};
        }
    }

    // initial hidden states (in regs, selected at t==0 / t==2)
    v2f hinit = {0.f, 0.f};
    if (wv < 2) hinit = *reinterpret_cast<const v2f*>(&h00[2 * l]);
    else if (wv < 4) hinit = *reinterpret_cast<const v2f*>(&h01[2 * l]);

    // xin0 wave: x prefetch regs (depth 3) + prologue xin0[0]
    float xA = 0.f, xB = 0.f, xC = 0.f;
    if (wv == 6) {
        const size_t base = (size_t)b * INDIM + l;
        float x0 = seq[base];
        xA = seq[(size_t)1 * BATCH * INDIM + base];
        xB = seq[(size_t)2 * BATCH * INDIM + base];
        xC = seq[(size_t)3 * BATCH * INDIM + base];
        x0ring[0][l] = dot64_single(w2, x0);      // xin0[0] -> slot (0-... read at t=1, slot 0
    }
    __syncthreads();

    const size_t YSZ = (size_t)SEQT * BATCH * HDIM;
    v2f h2 = hinit;   // persistent per-wave h register (rec waves)

    for (int t = 0; t <= SEQT + 2; ++t) {
        const int par = t & 1;

        if (wv < 2) {
            // ================= rec0 =================
            if (t >= 1 && t <= SEQT) {
                // combine h0[t-1] = gelu(red0a + red0b + xin0[t-1])
                v2f s = red0[par ^ 1][0][l] + red0[par ^ 1][1][l] + x0ring[(t - 1) & 3][l];
                h2.x = gelu_exact(s.x);
                h2.y = gelu_exact(s.y);
                if (wv == 1) h0buf[(t - 1) & 1][l] = h2;      // publish for xin1 waves
                if (wv == 0 && t == SEQT)                      // final h0 hidden
                    *reinterpret_cast<v2f*>(&out[YSZ + (size_t)b * HDIM + 2 * l]) = h2;
            }
            if (t <= SEQT - 1) {
                // Wh0-slice @ h0[t-1] -> partial of h0[t]
                v2f acc = (wv == 0) ? dot64_pair<0>(w2, h2.x, h2.y)
                                    : dot64_pair<64>(w2, h2.x, h2.y);
                red0[par][wv & 1][l] = acc;
            }
        } else if (wv < 4) {
            // ================= rec1 =================
            if (t >= 3) {
                // combine h1[t-3] = gelu(red2a+red2b + red1a+red1b)
                v2f s = red2[par ^ 1][0][l] + red2[par ^ 1][1][l]
                      + red1[par ^ 1][0][l] + red1[par ^ 1][1][l];
                h2.x = gelu_exact(s.x);
                h2.y = gelu_exact(s.y);
                if (wv == 2) {
                    const int tt = t - 3;
                    *reinterpret_cast<v2f*>(&out[((size_t)tt * BATCH + b) * HDIM + 2 * l]) = h2;
                    if (t == SEQT + 2)                          // final h1 hidden
                        *reinterpret_cast<v2f*>(
                            &out[YSZ + (size_t)BATCH * HDIM + (size_t)b * HDIM + 2 * l]) = h2;
                }
            }
            if (t >= 2 && t <= SEQT + 1) {
                // Wh1-slice @ h1[t-3] -> partial of h1[t-2]
                v2f acc = (wv == 2) ? dot64_pair<0>(w2, h2.x, h2.y)
                                    : dot64_pair<64>(w2, h2.x, h2.y);
                red2[par][wv & 1][l] = acc;
            }
        } else if (wv < 6) {
            // ================= xin1 =================
            if (t >= 2 && t <= SEQT + 1) {
                const int kh = wv & 1;
                // h0[t-2][64*kh + l] : lane (32*kh + l/2), component l&1 of h0buf pairs
                v2f hp = h0buf[(t - 2) & 1][32 * kh + (l >> 1)];
                float vh = (l & 1) ? hp.y : hp.x;
                // simpler & equivalent: each lane reads its own scalar
                vh = reinterpret_cast<const float*>(h0buf[(t - 2) & 1])[64 * kh + l];
                v2f acc = dot64_single(w2, vh);
                red1[(t - 2) & 1][kh][l] = acc;               // xin1[t-2]
            }
        } else {
            // ================= xin0 =================
            if (t <= SEQT - 2) {
                v2f acc = dot64_single(w2, xA);               // Win0 @ x[t+1]
                x0ring[(t + 1) & 3][l] = acc;
                xA = xB; xB = xC;
                int tn = t + 4; if (tn > SEQT - 1) tn = SEQT - 1;
                xC = seq[(size_t)tn * BATCH * INDIM + (size_t)b * INDIM + l];
            }
        }
        __syncthreads();
    }
}

extern "C" void kernel_launch(void* const* d_in, const int* in_sizes, int n_in,
                              void* d_out, int out_size, void* d_ws, size_t ws_size,
                              hipStream_t stream) {
    const float* seq  = (const float*)d_in[0];
    const float* Win0 = (const float*)d_in[1];
    const float* Wh0  = (const float*)d_in[2];
    const float* Win1 = (const float*)d_in[3];
    const float* Wh1  = (const float*)d_in[4];
    const float* h00  = (const float*)d_in[5];
    const float* h01  = (const float*)d_in[6];

    rnn_scan_kernel<<<dim3(BATCH), dim3(448), 0, stream>>>(
        seq, Win0, Wh0, Win1, Wh1, h00, h01, (float*)d_out);
}

// Round 5
// 1510.550 us; speedup vs baseline: 19.4499x; 1.0810x over previous
//
#include <hip/hip_runtime.h>
#include <math.h>

#define SEQT 2048
#define BATCH 256
#define INDIM 64
#define HDIM 128

typedef float v2f __attribute__((ext_vector_type(2)));

// exact GELU (approximate=False): 0.5*x*(1+erf(x/sqrt(2)))
__device__ __forceinline__ float gelu_exact(float x) {
    return 0.5f * x * (1.0f + erff(x * 0.70710678118654752f));
}

__device__ __forceinline__ v2f gelu2(v2f s) {
    v2f r;
    r.x = gelu_exact(s.x);
    r.y = gelu_exact(s.y);
    return r;
}

// 64-K dot, 2 outputs per lane. h broadcast via uniform-address LDS reads:
// ds_read_b128 at a wave-uniform address is a hardware broadcast (no bank
// conflict) and delivers 4 h values per DS instruction — zero VALU cost.
// VALU work: 64 v_pk_fma_f32 (128 MACs).
__device__ __forceinline__ v2f dotu64(const v2f* __restrict__ w2, const float* hsrc) {
    v2f a0 = {0.f, 0.f}, a1 = {0.f, 0.f}, a2 = {0.f, 0.f}, a3 = {0.f, 0.f};
    #pragma unroll
    for (int j = 0; j < 64; j += 4) {
        float4 hv = *reinterpret_cast<const float4*>(&hsrc[j]);
        a0 = __builtin_elementwise_fma(w2[j],     (v2f){hv.x, hv.x}, a0);
        a1 = __builtin_elementwise_fma(w2[j + 1], (v2f){hv.y, hv.y}, a1);
        a2 = __builtin_elementwise_fma(w2[j + 2], (v2f){hv.z, hv.z}, a2);
        a3 = __builtin_elementwise_fma(w2[j + 3], (v2f){hv.w, hv.w}, a3);
    }
    return (a0 + a1) + (a2 + a3);
}

// One workgroup per batch row. 448 threads = 7 waves, ONE barrier per step.
// Lane l owns outputs 2l, 2l+1 (float2 weights w2[64]).
//   wv0/1: rec0 kh={0,1}: combine h0[t-1] (gelu) then Wh0-slice @ h0[t-1]
//   wv2/3: rec1 kh={0,1}: combine h1[t-3] (gelu, stream y1) then Wh1 @ h1[t-3]
//   wv4/5: xin1 kh={0,1}: Win1-slice @ h0[t-2] (via shared h0buf)
//   wv6  : xin0: Win0 @ x[t+1] (x staged in LDS ring)
// SIMD pairing (wv%4): {rec0,xin1} {rec0,xin1} {rec1,xin0} {rec1}.
// h state lives in per-wave LDS copies: ds_write then same-wave uniform
// read-back (lgkmcnt ordering only, no extra barrier).
__global__ __launch_bounds__(448, 1)
void rnn_scan_kernel(
    const float* __restrict__ seq,
    const float* __restrict__ Win0, const float* __restrict__ Wh0,
    const float* __restrict__ Win1, const float* __restrict__ Wh1,
    const float* __restrict__ h00, const float* __restrict__ h01,
    float* __restrict__ out)
{
    const int b = blockIdx.x;
    const int tid = threadIdx.x;
    const int wv = tid >> 6;
    const int l = tid & 63;

    __shared__ __align__(16) v2f red0[2][2][64];    // rec0 partials [parity][kh][lane]
    __shared__ __align__(16) v2f red1[2][2][64];    // xin1 partials
    __shared__ __align__(16) v2f red2[2][2][64];    // rec1 partials
    __shared__ __align__(16) v2f x0ring[4][64];     // xin0 results (depth-4 ring)
    __shared__ __align__(16) float h0buf[2][HDIM];  // h0 history for xin1 (uniform-read)
    __shared__ __align__(16) float hc[4][HDIM];     // per-wave private h copies (wv0..3)
    __shared__ __align__(16) float xring[4][INDIM]; // staged x (wave 6 private)

    // ---- per-lane weight slice: rows 2l, 2l+1 interleaved as float2 ----
    v2f w2[64];
    {
        const float* W;
        int stride, c0;
        if (wv < 2)      { W = Wh0;  stride = HDIM;  c0 = (wv & 1) * 64; }
        else if (wv < 4) { W = Wh1;  stride = HDIM;  c0 = (wv & 1) * 64; }
        else if (wv < 6) { W = Win1; stride = HDIM;  c0 = (wv & 1) * 64; }
        else             { W = Win0; stride = INDIM; c0 = 0; }
        const float* ra = &W[(2 * l) * stride + c0];
        const float* rb = &W[(2 * l + 1) * stride + c0];
        #pragma unroll
        for (int j = 0; j < 64; j += 4) {
            float4 a = *reinterpret_cast<const float4*>(&ra[j]);
            float4 bq = *reinterpret_cast<const float4*>(&rb[j]);
            w2[j]     = (v2f){a.x, bq.x};
            w2[j + 1] = (v2f){a.y, bq.y};
            w2[j + 2] = (v2f){a.z, bq.z};
            w2[j + 3] = (v2f){a.w, bq.w};
        }
    }

    // ---- init h copies and x staging ----
    float xC = 0.f;
    if (wv < 2) {
        *reinterpret_cast<v2f*>(&hc[wv][2 * l]) = *reinterpret_cast<const v2f*>(&h00[2 * l]);
    } else if (wv < 4) {
        *reinterpret_cast<v2f*>(&hc[wv][2 * l]) = *reinterpret_cast<const v2f*>(&h01[2 * l]);
    } else if (wv == 6) {
        const size_t base = (size_t)b * INDIM + l;
        xring[0][l] = seq[base];
        xring[1][l] = seq[(size_t)1 * BATCH * INDIM + base];
        xring[2][l] = seq[(size_t)2 * BATCH * INDIM + base];
        xC          = seq[(size_t)3 * BATCH * INDIM + base];
        // prologue: xin0[0] (same-wave write->uniform-read, lgkmcnt orders)
        x0ring[0][l] = dotu64(w2, &xring[0][0]);
    }
    __syncthreads();

    const size_t YSZ = (size_t)SEQT * BATCH * HDIM;

    for (int t = 0; t <= SEQT + 2; ++t) {
        const int par = t & 1;

        if (wv < 2) {
            // ================= rec0 =================
            if (t >= 1 && t <= SEQT) {
                v2f s = red0[par ^ 1][0][l] + red0[par ^ 1][1][l] + x0ring[(t - 1) & 3][l];
                v2f h2 = gelu2(s);                              // h0[t-1]
                *reinterpret_cast<v2f*>(&hc[wv][2 * l]) = h2;
                if (wv == 1) *reinterpret_cast<v2f*>(&h0buf[(t - 1) & 1][2 * l]) = h2;
                if (wv == 0 && t == SEQT)
                    *reinterpret_cast<v2f*>(&out[YSZ + (size_t)b * HDIM + 2 * l]) = h2;
            }
            if (t <= SEQT - 1) {
                v2f acc = dotu64(w2, &hc[wv][(wv & 1) * 64]);   // Wh0-slice @ h0[t-1]
                red0[par][wv & 1][l] = acc;
            }
        } else if (wv < 4) {
            // ================= rec1 =================
            if (t >= 3) {
                v2f s = red2[par ^ 1][0][l] + red2[par ^ 1][1][l]
                      + red1[par ^ 1][0][l] + red1[par ^ 1][1][l];
                v2f h2 = gelu2(s);                              // h1[t-3]
                *reinterpret_cast<v2f*>(&hc[wv][2 * l]) = h2;
                if (wv == 2) {
                    const int tt = t - 3;
                    *reinterpret_cast<v2f*>(&out[((size_t)tt * BATCH + b) * HDIM + 2 * l]) = h2;
                    if (t == SEQT + 2)
                        *reinterpret_cast<v2f*>(
                            &out[YSZ + (size_t)BATCH * HDIM + (size_t)b * HDIM + 2 * l]) = h2;
                }
            }
            if (t >= 2 && t <= SEQT + 1) {
                v2f acc = dotu64(w2, &hc[wv][(wv & 1) * 64]);   // Wh1-slice @ h1[t-3]
                red2[par][wv & 1][l] = acc;
            }
        } else if (wv < 6) {
            // ================= xin1 =================
            if (t >= 2 && t <= SEQT + 1) {
                const int kh = wv & 1;
                v2f acc = dotu64(w2, &h0buf[(t - 2) & 1][kh * 64]);  // Win1 @ h0[t-2]
                red1[(t - 2) & 1][kh][l] = acc;
            }
        } else {
            // ================= xin0 =================
            if (t <= SEQT - 2) {
                v2f acc = dotu64(w2, &xring[(t + 1) & 3][0]);   // Win0 @ x[t+1]
                x0ring[(t + 1) & 3][l] = acc;
                if (t + 3 <= SEQT - 1) {
                    xring[(t + 3) & 3][l] = xC;                 // stage x[t+3]
                    int tn = t + 4; if (tn > SEQT - 1) tn = SEQT - 1;
                    xC = seq[(size_t)tn * BATCH * INDIM + (size_t)b * INDIM + l];
                }
            }
        }
        __syncthreads();
    }
}

extern "C" void kernel_launch(void* const* d_in, const int* in_sizes, int n_in,
                              void* d_out, int out_size, void* d_ws, size_t ws_size,
                              hipStream_t stream) {
    const float* seq  = (const float*)d_in[0];
    const float* Win0 = (const float*)d_in[1];
    const float* Wh0  = (const float*)d_in[2];
    const float* Win1 = (const float*)d_in[3];
    const float* Wh1  = (const float*)d_in[4];
    const float* h00  = (const float*)d_in[5];
    const float* h01  = (const float*)d_in[6];

    rnn_scan_kernel<<<dim3(BATCH), dim3(448), 0, stream>>>(
        seq, Win0, Wh0, Win1, Wh1, h00, h01, (float*)d_out);
}

// Round 7
// 1215.349 us; speedup vs baseline: 24.1742x; 1.2429x over previous
//
#include <hip/hip_runtime.h>
#include <math.h>

#define SEQT 2048
#define BATCH 256
#define INDIM 64
#define HDIM 128

typedef float v2f __attribute__((ext_vector_type(2)));

// ---- fast branch-free erf (Abramowitz-Stegun 7.1.26, |abs err| <= 1.5e-7) ----
// gelu(x) = 0.5*x*(1 + erf(x/sqrt(2))) = 0.5*x + 0.5*|x|*erf(|x|/sqrt2)
__device__ __forceinline__ float gelu_fast(float x) {
    const float ax = __builtin_fabsf(x);
    const float z  = ax * 0.70710678118654752f;
    // t = 1/(1 + 0.3275911 z)   (HW rcp; error budget is huge)
    const float t  = __builtin_amdgcn_rcpf(__builtin_fmaf(0.3275911f, z, 1.0f));
    float p = __builtin_fmaf(1.061405429f, t, -1.453152027f);
    p = __builtin_fmaf(p, t, 1.421413741f);
    p = __builtin_fmaf(p, t, -0.284496736f);
    p = __builtin_fmaf(p, t, 0.254829592f);
    p = p * t;
    // exp(-z^2) = 2^(-z^2 * log2(e))   (v_exp_f32 computes 2^x)
    const float e = __builtin_amdgcn_exp2f(z * z * -1.44269504088896f);
    const float erfv = __builtin_fmaf(-p, e, 1.0f);     // erf(z), z>=0
    return __builtin_fmaf(0.5f * ax, erfv, 0.5f * x);
}

__device__ __forceinline__ v2f gelu2(v2f s) {
    v2f r;
    r.x = gelu_fast(s.x);
    r.y = gelu_fast(s.y);
    return r;
}

// ---- packed FMA with explicit word-broadcast of src1 (no splat movs) ----
// acc += w * broadcast(word0(hp))
__device__ __forceinline__ void pk_lo(v2f& acc, v2f w, v2f hp) {
    asm("v_pk_fma_f32 %0, %1, %2, %0 op_sel:[0,0,0] op_sel_hi:[1,0,1]"
        : "+v"(acc) : "v"(w), "v"(hp));
}
// acc += w * broadcast(word1(hp))
__device__ __forceinline__ void pk_hi(v2f& acc, v2f w, v2f hp) {
    asm("v_pk_fma_f32 %0, %1, %2, %0 op_sel:[0,1,0] op_sel_hi:[1,1,1]"
        : "+v"(acc) : "v"(w), "v"(hp));
}

// 64-K dot, 2 outputs per lane. h broadcast via uniform-address LDS reads
// (hardware broadcast, no bank conflict). VALU: exactly 64 v_pk_fma_f32.
__device__ __forceinline__ v2f dotu64(const v2f* __restrict__ w2, const float* hsrc) {
    v2f a0 = {0.f, 0.f}, a1 = {0.f, 0.f}, a2 = {0.f, 0.f}, a3 = {0.f, 0.f};
    #pragma unroll
    for (int j = 0; j < 64; j += 4) {
        v2f p0 = *reinterpret_cast<const v2f*>(&hsrc[j]);       // {h[j],   h[j+1]}
        v2f p1 = *reinterpret_cast<const v2f*>(&hsrc[j + 2]);   // {h[j+2], h[j+3]}
        pk_lo(a0, w2[j],     p0);
        pk_hi(a1, w2[j + 1], p0);
        pk_lo(a2, w2[j + 2], p1);
        pk_hi(a3, w2[j + 3], p1);
    }
    return (a0 + a1) + (a2 + a3);
}

// One workgroup per batch row. 448 threads = 7 waves, ONE barrier per step.
// Lane l owns outputs 2l, 2l+1 (float2 weights w2[64]).
//   wv0/1: rec0 kh={0,1}: combine h0[t-1] (gelu) then Wh0-slice @ h0[t-1]
//   wv2/3: rec1 kh={0,1}: combine h1[t-3] (gelu, stream y1) then Wh1 @ h1[t-3]
//   wv4/5: xin1 kh={0,1}: Win1-slice @ h0[t-2] (via shared h0buf)
//   wv6  : xin0: Win0 @ x[t+1] (x staged in LDS ring)
__global__ __launch_bounds__(448, 1)
__attribute__((amdgpu_waves_per_eu(1, 2)))
void rnn_scan_kernel(
    const float* __restrict__ seq,
    const float* __restrict__ Win0, const float* __restrict__ Wh0,
    const float* __restrict__ Win1, const float* __restrict__ Wh1,
    const float* __restrict__ h00, const float* __restrict__ h01,
    float* __restrict__ out)
{
    const int b = blockIdx.x;
    const int tid = threadIdx.x;
    const int wv = tid >> 6;
    const int l = tid & 63;

    __shared__ __align__(16) v2f red0[2][2][64];    // rec0 partials [parity][kh][lane]
    __shared__ __align__(16) v2f red1[2][2][64];    // xin1 partials
    __shared__ __align__(16) v2f red2[2][2][64];    // rec1 partials
    __shared__ __align__(16) v2f x0ring[4][64];     // xin0 results (depth-4 ring)
    __shared__ __align__(16) float h0buf[2][HDIM];  // h0 history for xin1 (uniform-read)
    __shared__ __align__(16) float hc[4][HDIM];     // per-wave private h copies (wv0..3)
    __shared__ __align__(16) float xring[4][INDIM]; // staged x (wave 6 private)

    // ---- per-lane weight slice: rows 2l, 2l+1 interleaved as float2 ----
    v2f w2[64];
    {
        const float* W;
        int stride, c0;
        if (wv < 2)      { W = Wh0;  stride = HDIM;  c0 = (wv & 1) * 64; }
        else if (wv < 4) { W = Wh1;  stride = HDIM;  c0 = (wv & 1) * 64; }
        else if (wv < 6) { W = Win1; stride = HDIM;  c0 = (wv & 1) * 64; }
        else             { W = Win0; stride = INDIM; c0 = 0; }
        const float* ra = &W[(2 * l) * stride + c0];
        const float* rb = &W[(2 * l + 1) * stride + c0];
        #pragma unroll
        for (int j = 0; j < 64; j += 4) {
            float4 a = *reinterpret_cast<const float4*>(&ra[j]);
            float4 bq = *reinterpret_cast<const float4*>(&rb[j]);
            w2[j]     = (v2f){a.x, bq.x};
            w2[j + 1] = (v2f){a.y, bq.y};
            w2[j + 2] = (v2f){a.z, bq.z};
            w2[j + 3] = (v2f){a.w, bq.w};
        }
    }

    // ---- init h copies and x staging ----
    float xC = 0.f;
    if (wv < 2) {
        *reinterpret_cast<v2f*>(&hc[wv][2 * l]) = *reinterpret_cast<const v2f*>(&h00[2 * l]);
    } else if (wv < 4) {
        *reinterpret_cast<v2f*>(&hc[wv][2 * l]) = *reinterpret_cast<const v2f*>(&h01[2 * l]);
    } else if (wv == 6) {
        const size_t base = (size_t)b * INDIM + l;
        xring[0][l] = seq[base];
        xring[1][l] = seq[(size_t)1 * BATCH * INDIM + base];
        xring[2][l] = seq[(size_t)2 * BATCH * INDIM + base];
        xC          = seq[(size_t)3 * BATCH * INDIM + base];
        // prologue: xin0[0] (same-wave write->uniform-read, lgkmcnt orders)
        x0ring[0][l] = dotu64(w2, &xring[0][0]);
    }
    __syncthreads();

    const size_t YSZ = (size_t)SEQT * BATCH * HDIM;

    for (int t = 0; t <= SEQT + 2; ++t) {
        const int par = t & 1;

        if (wv < 2) {
            // ================= rec0 =================
            if (t >= 1 && t <= SEQT) {
                v2f s = red0[par ^ 1][0][l] + red0[par ^ 1][1][l] + x0ring[(t - 1) & 3][l];
                v2f h2 = gelu2(s);                              // h0[t-1]
                *reinterpret_cast<v2f*>(&hc[wv][2 * l]) = h2;
                if (wv == 1) *reinterpret_cast<v2f*>(&h0buf[(t - 1) & 1][2 * l]) = h2;
                if (wv == 0 && t == SEQT)
                    *reinterpret_cast<v2f*>(&out[YSZ + (size_t)b * HDIM + 2 * l]) = h2;
            }
            if (t <= SEQT - 1) {
                v2f acc = dotu64(w2, &hc[wv][(wv & 1) * 64]);   // Wh0-slice @ h0[t-1]
                red0[par][wv & 1][l] = acc;
            }
        } else if (wv < 4) {
            // ================= rec1 =================
            if (t >= 3) {
                v2f s = red2[par ^ 1][0][l] + red2[par ^ 1][1][l]
                      + red1[par ^ 1][0][l] + red1[par ^ 1][1][l];
                v2f h2 = gelu2(s);                              // h1[t-3]
                *reinterpret_cast<v2f*>(&hc[wv][2 * l]) = h2;
                if (wv == 2) {
                    const int tt = t - 3;
                    *reinterpret_cast<v2f*>(&out[((size_t)tt * BATCH + b) * HDIM + 2 * l]) = h2;
                    if (t == SEQT + 2)
                        *reinterpret_cast<v2f*>(
                            &out[YSZ + (size_t)BATCH * HDIM + (size_t)b * HDIM + 2 * l]) = h2;
                }
            }
            if (t >= 2 && t <= SEQT + 1) {
                v2f acc = dotu64(w2, &hc[wv][(wv & 1) * 64]);   // Wh1-slice @ h1[t-3]
                red2[par][wv & 1][l] = acc;
            }
        } else if (wv < 6) {
            // ================= xin1 =================
            if (t >= 2 && t <= SEQT + 1) {
                const int kh = wv & 1;
                v2f acc = dotu64(w2, &h0buf[(t - 2) & 1][kh * 64]);  // Win1 @ h0[t-2]
                red1[(t - 2) & 1][kh][l] = acc;
            }
        } else {
            // ================= xin0 =================
            if (t <= SEQT - 2) {
                v2f acc = dotu64(w2, &xring[(t + 1) & 3][0]);   // Win0 @ x[t+1]
                x0ring[(t + 1) & 3][l] = acc;
                if (t + 3 <= SEQT - 1) {
                    xring[(t + 3) & 3][l] = xC;                 // stage x[t+3]
                    int tn = t + 4; if (tn > SEQT - 1) tn = SEQT - 1;
                    xC = seq[(size_t)tn * BATCH * INDIM + (size_t)b * INDIM + l];
                }
            }
        }
        __syncthreads();
    }
}

extern "C" void kernel_launch(void* const* d_in, const int* in_sizes, int n_in,
                              void* d_out, int out_size, void* d_ws, size_t ws_size,
                              hipStream_t stream) {
    const float* seq  = (const float*)d_in[0];
    const float* Win0 = (const float*)d_in[1];
    const float* Wh0  = (const float*)d_in[2];
    const float* Win1 = (const float*)d_in[3];
    const float* Wh1  = (const float*)d_in[4];
    const float* h00  = (const float*)d_in[5];
    const float* h01  = (const float*)d_in[6];

    rnn_scan_kernel<<<dim3(BATCH), dim3(448), 0, stream>>>(
        seq, Win0, Wh0, Win1, Wh1, h00, h01, (float*)d_out);
}